// Round 1
// baseline (823.449 us; speedup 1.0000x reference)
//
#include <hip/hip_runtime.h>

// ArmaCell: B=1024, K=256, UNITS=32, P=4, Q=4
//   ar[b,j,u] = sum_{i,p} inputs[b,i,p]   * kernel[p,u,i,j]
//   ma[b,j,u] = sum_{i,q} state[b,i*32+u,q]* rk[q,u,i,j]
//   out[b, j*32+u] = ar+ma ; out_state = concat(out, state[:,:,:3])
//
// Per-u fused GEMM: C_u(1024x256) = A(1024x1024)@K_u(1024x256) + M_u(1024x1024)@R_u(1024x256)

#define BM 64
#define BN 64
#define BK 16
#define LDP 68  // padded leading dim (multiple of 4 -> 16B-aligned float4 LDS access)

__global__ __launch_bounds__(256) void arma_gemm(
    const float* __restrict__ inputs,   // (1024, 256, 4)
    const float* __restrict__ state,    // (1024, 8192, 4)
    const float* __restrict__ kern,     // (4, 32, 256, 256)
    const float* __restrict__ rkern,    // (4, 32, 256, 256)
    float* __restrict__ out)            // (1024, 8192)
{
    const int u   = blockIdx.z;
    const int b0  = blockIdx.x * BM;
    const int j0  = blockIdx.y * BN;
    const int tid = threadIdx.x;

    __shared__ float As[BK][LDP];   // [k_local][b_local]
    __shared__ float Ws[BK][LDP];   // [k_local][j_local]

    const int tx = tid & 15;        // j micro-tile
    const int ty = tid >> 4;        // b micro-tile

    // A-tile staging: 64 rows x 16 k, one float4 per thread
    const int arow = tid >> 2;          // 0..63
    const int ak4  = (tid & 3) * 4;     // k_local base 0/4/8/12

    // W-tile staging: 16 k x 64 j, one float4 per thread
    const int wrow = tid >> 4;          // 0..15 (k_local)
    const int wj   = (tid & 15) * 4;    // j_local base

    float acc[4][4] = {{0.f}};

    // ---------------- Phase 1: AR  (contraction ip = i*4+p, 1024 deep) ----------------
    for (int kt = 0; kt < 1024; kt += BK) {
        // A[b, ip] = inputs[b*1024 + ip]  (contiguous in ip)
        {
            const float4 av = *(const float4*)(inputs + (size_t)(b0 + arow) * 1024 + kt + ak4);
            As[ak4 + 0][arow] = av.x;
            As[ak4 + 1][arow] = av.y;
            As[ak4 + 2][arow] = av.z;
            As[ak4 + 3][arow] = av.w;
        }
        // W[ip, j] = kern[((p*32+u)*256 + i)*256 + j], i=ip>>2, p=ip&3
        {
            const int ip = kt + wrow;
            const int i  = ip >> 2;
            const int p  = ip & 3;
            const float4 wv = *(const float4*)(kern + ((size_t)((p * 32 + u) * 256 + i)) * 256 + j0 + wj);
            *(float4*)&Ws[wrow][wj] = wv;
        }
        __syncthreads();
        #pragma unroll
        for (int kk = 0; kk < BK; ++kk) {
            const float4 a4 = *(const float4*)&As[kk][ty * 4];
            const float4 w4 = *(const float4*)&Ws[kk][tx * 4];
            acc[0][0] += a4.x * w4.x; acc[0][1] += a4.x * w4.y; acc[0][2] += a4.x * w4.z; acc[0][3] += a4.x * w4.w;
            acc[1][0] += a4.y * w4.x; acc[1][1] += a4.y * w4.y; acc[1][2] += a4.y * w4.z; acc[1][3] += a4.y * w4.w;
            acc[2][0] += a4.z * w4.x; acc[2][1] += a4.z * w4.y; acc[2][2] += a4.z * w4.z; acc[2][3] += a4.z * w4.w;
            acc[3][0] += a4.w * w4.x; acc[3][1] += a4.w * w4.y; acc[3][2] += a4.w * w4.z; acc[3][3] += a4.w * w4.w;
        }
        __syncthreads();
    }

    // ---------------- Phase 2: MA  (contraction iq = i*4+q, 1024 deep) ----------------
    for (int kt = 0; kt < 1024; kt += BK) {
        // M[b, iq] = state[b*32768 + (i*32+u)*4 + q]; per i, q0..3 contiguous -> float4
        {
            const int i = (kt >> 2) + (tid & 3);
            const float4 av = *(const float4*)(state + (size_t)(b0 + arow) * 32768 + (size_t)(i * 32 + u) * 4);
            As[ak4 + 0][arow] = av.x;   // q=0
            As[ak4 + 1][arow] = av.y;   // q=1
            As[ak4 + 2][arow] = av.z;   // q=2
            As[ak4 + 3][arow] = av.w;   // q=3
        }
        // W[iq, j] = rkern[((q*32+u)*256 + i)*256 + j], i=iq>>2, q=iq&3
        {
            const int iq = kt + wrow;
            const int i  = iq >> 2;
            const int q  = iq & 3;
            const float4 wv = *(const float4*)(rkern + ((size_t)((q * 32 + u) * 256 + i)) * 256 + j0 + wj);
            *(float4*)&Ws[wrow][wj] = wv;
        }
        __syncthreads();
        #pragma unroll
        for (int kk = 0; kk < BK; ++kk) {
            const float4 a4 = *(const float4*)&As[kk][ty * 4];
            const float4 w4 = *(const float4*)&Ws[kk][tx * 4];
            acc[0][0] += a4.x * w4.x; acc[0][1] += a4.x * w4.y; acc[0][2] += a4.x * w4.z; acc[0][3] += a4.x * w4.w;
            acc[1][0] += a4.y * w4.x; acc[1][1] += a4.y * w4.y; acc[1][2] += a4.y * w4.z; acc[1][3] += a4.y * w4.w;
            acc[2][0] += a4.z * w4.x; acc[2][1] += a4.z * w4.y; acc[2][2] += a4.z * w4.z; acc[2][3] += a4.z * w4.w;
            acc[3][0] += a4.w * w4.x; acc[3][1] += a4.w * w4.y; acc[3][2] += a4.w * w4.z; acc[3][3] += a4.w * w4.w;
        }
        __syncthreads();
    }

    // Epilogue: out[b, j*32+u]  (scattered 4B writes; measure amplification this round)
    const int bb = b0 + ty * 4;
    const int jj = j0 + tx * 4;
    #pragma unroll
    for (int r = 0; r < 4; ++r) {
        #pragma unroll
        for (int c = 0; c < 4; ++c) {
            out[(size_t)(bb + r) * 8192 + (size_t)(jj + c) * 32 + u] = acc[r][c];
        }
    }
}

// out_state[b,n,:] = { out[b,n], state[b,n,0], state[b,n,1], state[b,n,2] }
__global__ __launch_bounds__(256) void arma_assemble(
    const float* __restrict__ state,
    const float* __restrict__ out,
    float* __restrict__ out_state)
{
    const size_t idx = (size_t)blockIdx.x * 256 + threadIdx.x;  // over B*N = 8388608
    const float4 s = *(const float4*)(state + idx * 4);
    const float  o = out[idx];
    float4 r;
    r.x = o; r.y = s.x; r.z = s.y; r.w = s.z;
    *(float4*)(out_state + idx * 4) = r;
}

extern "C" void kernel_launch(void* const* d_in, const int* in_sizes, int n_in,
                              void* d_out, int out_size, void* d_ws, size_t ws_size,
                              hipStream_t stream) {
    const float* inputs = (const float*)d_in[0];
    const float* state  = (const float*)d_in[1];
    const float* kern   = (const float*)d_in[2];
    const float* rkern  = (const float*)d_in[3];

    float* out       = (float*)d_out;              // (1024, 8192, 1) flat
    float* out_state = (float*)d_out + 8388608;    // (1024, 8192, 4) flat

    dim3 grid(1024 / BM, 256 / BN, 32);  // (16, 4, 32)
    arma_gemm<<<grid, 256, 0, stream>>>(inputs, state, kern, rkern, out);

    arma_assemble<<<8388608 / 256, 256, 0, stream>>>(state, out, out_state);
}

// Round 3
// 635.763 us; speedup vs baseline: 1.2952x; 1.2952x over previous
//
#include <hip/hip_runtime.h>
#include <hip/hip_bf16.h>

// ArmaCell: B=1024, K=256, UNITS=32, P=4, Q=4
// out[b, j*32+u] = sum_{i,p} inputs[b,i*4+p]*kernel[p,u,i,j]
//                + sum_{i,q} state[b,(i*32+u)*4+q]*rk[q,u,i,j]
// out_state[b,n,:] = { out[b,n], state[b,n,0..2] }
//
// bf16 MFMA path: per u, C(1024x256) = A(1024x2048) @ W_u(2048x256),
// W pre-transposed to Wt[u][j][k] bf16 (k-contiguous, B^T layout) in d_ws.

typedef __attribute__((ext_vector_type(8))) short bf16x8;
typedef __attribute__((ext_vector_type(4))) float f32x4;

__device__ inline unsigned short f2bf(float x) {
    unsigned int u = __float_as_uint(x);
    return (unsigned short)((u + 0x7fffu + ((u >> 16) & 1u)) >> 16);
}

__device__ inline void cvt_store4(unsigned short* dst, float4 v) {
    float2 ab; ab.x = v.x; ab.y = v.y;
    float2 cd; cd.x = v.z; cd.y = v.w;
    __hip_bfloat162 lo = __float22bfloat162_rn(ab);   // v_cvt_pk_bf16_f32
    __hip_bfloat162 hi = __float22bfloat162_rn(cd);
    union { __hip_bfloat162 h2[2]; uint2 u2; } pk;
    pk.h2[0] = lo; pk.h2[1] = hi;
    *(uint2*)dst = pk.u2;   // 8B aligned by construction
}

// ---------------- Pre-pass: Wt[u][j][k] bf16, k = (AR: i*4+p) | (MA: 1024 + i*4+q)
__global__ __launch_bounds__(256) void prep_w(
    const float* __restrict__ kern,    // (4,32,256,256) [p][u][i][j]
    const float* __restrict__ rkern,   // (4,32,256,256) [q][u][i][j]
    unsigned short* __restrict__ Wt)   // (32,256,2048)
{
    const int u  = blockIdx.x;
    const int j0 = blockIdx.y * 64;
    const int zz = blockIdx.z;         // 0..31
    const int mm = zz >> 4;            // 0=kern, 1=rkern
    const int it = zz & 15;            // i-tile (16 i's -> 64 k's)
    const float* src = mm ? rkern : kern;
    const int kout = mm * 1024 + it * 64;

    __shared__ unsigned short T[64 * 72];   // [j][kk], pitch 72

    const int t  = threadIdx.x;
    const int c  = t & 63;
    const int ii = c >> 2, pp = c & 3;
    const int i  = it * 16 + ii;
    const int kk = ii * 4 + pp;        // 0..63
    const int jq = t >> 6;             // 0..3
    const float* row = src + ((size_t)((pp * 32 + u) * 256 + i)) * 256 + j0 + jq * 16;
    #pragma unroll
    for (int s = 0; s < 4; ++s) {
        float4 v = *(const float4*)(row + s * 4);
        const int jb = jq * 16 + s * 4;
        T[(jb + 0) * 72 + kk] = f2bf(v.x);
        T[(jb + 1) * 72 + kk] = f2bf(v.y);
        T[(jb + 2) * 72 + kk] = f2bf(v.z);
        T[(jb + 3) * 72 + kk] = f2bf(v.w);
    }
    __syncthreads();
    const int j = t >> 2, q = t & 3;
    unsigned short* dst = Wt + ((size_t)(u * 256 + j0 + j)) * 2048 + kout + q * 16;
    uint4 a = *(uint4*)&T[j * 72 + q * 16];
    uint4 b = *(uint4*)&T[j * 72 + q * 16 + 8];
    *(uint4*)dst = a;
    *(uint4*)(dst + 8) = b;
}

// ---------------- MFMA GEMM: grid (8 m-blocks, 2 n-blocks, 32 u), 256 thr
#define PITCH 40   // bf16 pitch: 80B rows -> 2-way LDS conflicts only (free)

__global__ __launch_bounds__(256) void arma_gemm_mfma(
    const float* __restrict__ inputs,          // (1024,1024) fp32
    const float* __restrict__ state,           // (1024,32768) fp32
    const unsigned short* __restrict__ Wt,     // (32,256,2048) bf16
    float* __restrict__ out)                   // (1024,8192)
{
    const int u  = blockIdx.z;
    const int b0 = blockIdx.x * 128;
    const int j0 = blockIdx.y * 128;
    const int t  = threadIdx.x;
    const int lane = t & 63;
    const int wave = t >> 6;
    const int wm = (wave & 1) * 64;
    const int wn = (wave >> 1) * 64;
    const int fm = lane & 15;          // m (A) / n (B) within 16-tile
    const int kq = lane >> 4;          // k-quad: k = kq*8 + 0..7

    __shared__ unsigned short Asr[128 * PITCH];  // [b_local][k] bf16
    __shared__ unsigned short Wsr[128 * PITCH];  // [j_local][k] bf16

    const int arow = t >> 1;           // 0..127
    const int ak   = (t & 1) * 16;     // 0 | 16

    f32x4 acc[4][4];
    #pragma unroll
    for (int a = 0; a < 4; ++a)
        #pragma unroll
        for (int b = 0; b < 4; ++b)
            acc[a][b] = (f32x4)0.0f;

    const unsigned short* wsrc = Wt + ((size_t)(u * 256 + j0 + arow)) * 2048 + ak;
    const float* in_row = inputs + (size_t)(b0 + arow) * 1024 + ak;
    const float* st_row = state + (size_t)(b0 + arow) * 32768 + (size_t)u * 4;

    for (int kt = 0; kt < 2048; kt += 32) {
        float4 v0, v1, v2, v3;
        if (kt < 1024) {                      // AR phase: A from inputs, k-contiguous
            const float* s = in_row + kt;
            v0 = *(const float4*)(s);
            v1 = *(const float4*)(s + 4);
            v2 = *(const float4*)(s + 8);
            v3 = *(const float4*)(s + 12);
        } else {                              // MA phase: A from state, k=i*4+q
            const int kk = kt - 1024 + ak;
            const float* s = st_row + (size_t)(kk >> 2) * 128;
            v0 = *(const float4*)(s);
            v1 = *(const float4*)(s + 128);
            v2 = *(const float4*)(s + 256);
            v3 = *(const float4*)(s + 384);
        }
        uint4 w0 = *(const uint4*)(wsrc + kt);
        uint4 w1 = *(const uint4*)(wsrc + kt + 8);

        unsigned short* ad = &Asr[arow * PITCH + ak];
        cvt_store4(ad + 0,  v0);
        cvt_store4(ad + 4,  v1);
        cvt_store4(ad + 8,  v2);
        cvt_store4(ad + 12, v3);
        *(uint4*)&Wsr[arow * PITCH + ak] = w0;
        *(uint4*)&Wsr[arow * PITCH + ak + 8] = w1;

        __syncthreads();

        bf16x8 af[4], bfr[4];
        #pragma unroll
        for (int mt = 0; mt < 4; ++mt)
            af[mt] = *(const bf16x8*)&Asr[(wm + mt * 16 + fm) * PITCH + kq * 8];
        #pragma unroll
        for (int nt = 0; nt < 4; ++nt)
            bfr[nt] = *(const bf16x8*)&Wsr[(wn + nt * 16 + fm) * PITCH + kq * 8];
        #pragma unroll
        for (int mt = 0; mt < 4; ++mt)
            #pragma unroll
            for (int nt = 0; nt < 4; ++nt)
                acc[mt][nt] = __builtin_amdgcn_mfma_f32_16x16x32_bf16(
                    af[mt], bfr[nt], acc[mt][nt], 0, 0, 0);

        __syncthreads();
    }

    // Epilogue: C row=(kq*4+reg), col=fm; out[b, j*32+u] scattered 4B
    #pragma unroll
    for (int mt = 0; mt < 4; ++mt) {
        const int rbase = b0 + wm + mt * 16 + kq * 4;
        #pragma unroll
        for (int nt = 0; nt < 4; ++nt) {
            const int col = j0 + wn + nt * 16 + fm;
            float* op = out + (size_t)rbase * 8192 + (size_t)col * 32 + u;
            op[0]        = acc[mt][nt][0];
            op[8192]     = acc[mt][nt][1];
            op[2 * 8192] = acc[mt][nt][2];
            op[3 * 8192] = acc[mt][nt][3];
        }
    }
}

// ---------------- fp32 fallback GEMM (round-1 kernel, used only if ws too small)
#define BM 64
#define BN 64
#define BK 16
#define LDP 68

__global__ __launch_bounds__(256) void arma_gemm_f32(
    const float* __restrict__ inputs, const float* __restrict__ state,
    const float* __restrict__ kern, const float* __restrict__ rkern,
    float* __restrict__ out)
{
    const int u = blockIdx.z, b0 = blockIdx.x * BM, j0 = blockIdx.y * BN;
    const int tid = threadIdx.x;
    __shared__ float As[BK][LDP];
    __shared__ float Ws[BK][LDP];
    const int tx = tid & 15, ty = tid >> 4;
    const int arow = tid >> 2, ak4 = (tid & 3) * 4;
    const int wrow = tid >> 4, wj = (tid & 15) * 4;
    float acc[4][4] = {{0.f}};
    for (int kt = 0; kt < 1024; kt += BK) {
        const float4 av = *(const float4*)(inputs + (size_t)(b0 + arow) * 1024 + kt + ak4);
        As[ak4 + 0][arow] = av.x; As[ak4 + 1][arow] = av.y;
        As[ak4 + 2][arow] = av.z; As[ak4 + 3][arow] = av.w;
        const int ip = kt + wrow;
        const float4 wv = *(const float4*)(kern + ((size_t)(((ip & 3) * 32 + u) * 256 + (ip >> 2))) * 256 + j0 + wj);
        *(float4*)&Ws[wrow][wj] = wv;
        __syncthreads();
        #pragma unroll
        for (int kk = 0; kk < BK; ++kk) {
            const float4 a4 = *(const float4*)&As[kk][ty * 4];
            const float4 w4 = *(const float4*)&Ws[kk][tx * 4];
            acc[0][0] += a4.x * w4.x; acc[0][1] += a4.x * w4.y; acc[0][2] += a4.x * w4.z; acc[0][3] += a4.x * w4.w;
            acc[1][0] += a4.y * w4.x; acc[1][1] += a4.y * w4.y; acc[1][2] += a4.y * w4.z; acc[1][3] += a4.y * w4.w;
            acc[2][0] += a4.z * w4.x; acc[2][1] += a4.z * w4.y; acc[2][2] += a4.z * w4.z; acc[2][3] += a4.z * w4.w;
            acc[3][0] += a4.w * w4.x; acc[3][1] += a4.w * w4.y; acc[3][2] += a4.w * w4.z; acc[3][3] += a4.w * w4.w;
        }
        __syncthreads();
    }
    for (int kt = 0; kt < 1024; kt += BK) {
        const int i = (kt >> 2) + (tid & 3);
        const float4 av = *(const float4*)(state + (size_t)(b0 + arow) * 32768 + (size_t)(i * 32 + u) * 4);
        As[ak4 + 0][arow] = av.x; As[ak4 + 1][arow] = av.y;
        As[ak4 + 2][arow] = av.z; As[ak4 + 3][arow] = av.w;
        const int iq = kt + wrow;
        const float4 wv = *(const float4*)(rkern + ((size_t)(((iq & 3) * 32 + u) * 256 + (iq >> 2))) * 256 + j0 + wj);
        *(float4*)&Ws[wrow][wj] = wv;
        __syncthreads();
        #pragma unroll
        for (int kk = 0; kk < BK; ++kk) {
            const float4 a4 = *(const float4*)&As[kk][ty * 4];
            const float4 w4 = *(const float4*)&Ws[kk][tx * 4];
            acc[0][0] += a4.x * w4.x; acc[0][1] += a4.x * w4.y; acc[0][2] += a4.x * w4.z; acc[0][3] += a4.x * w4.w;
            acc[1][0] += a4.y * w4.x; acc[1][1] += a4.y * w4.y; acc[1][2] += a4.y * w4.z; acc[1][3] += a4.y * w4.w;
            acc[2][0] += a4.z * w4.x; acc[2][1] += a4.z * w4.y; acc[2][2] += a4.z * w4.z; acc[2][3] += a4.z * w4.w;
            acc[3][0] += a4.w * w4.x; acc[3][1] += a4.w * w4.y; acc[3][2] += a4.w * w4.z; acc[3][3] += a4.w * w4.w;
        }
        __syncthreads();
    }
    const int bb = b0 + ty * 4, jj = j0 + tx * 4;
    #pragma unroll
    for (int r = 0; r < 4; ++r)
        #pragma unroll
        for (int c = 0; c < 4; ++c)
            out[(size_t)(bb + r) * 8192 + (size_t)(jj + c) * 32 + u] = acc[r][c];
}

// ---------------- Assemble: out_state[b,n,:] = { out[b,n], state[b,n,0..2] }
__global__ __launch_bounds__(256) void arma_assemble2(
    const float* __restrict__ state,
    const float* __restrict__ out,
    float* __restrict__ out_state)
{
    const size_t i = (size_t)blockIdx.x * 256 + threadIdx.x;  // 0 .. B*N/4-1
    const f32x4 o = *(const f32x4*)(out + i * 4);
    const float* sp = state + i * 16;
    const f32x4 s0 = *(const f32x4*)(sp + 0);
    const f32x4 s1 = *(const f32x4*)(sp + 4);
    const f32x4 s2 = *(const f32x4*)(sp + 8);
    const f32x4 s3 = *(const f32x4*)(sp + 12);
    f32x4 r0 = { o[0], s0[0], s0[1], s0[2] };
    f32x4 r1 = { o[1], s1[0], s1[1], s1[2] };
    f32x4 r2 = { o[2], s2[0], s2[1], s2[2] };
    f32x4 r3 = { o[3], s3[0], s3[1], s3[2] };
    f32x4* dp = (f32x4*)(out_state + i * 16);
    __builtin_nontemporal_store(r0, dp + 0);
    __builtin_nontemporal_store(r1, dp + 1);
    __builtin_nontemporal_store(r2, dp + 2);
    __builtin_nontemporal_store(r3, dp + 3);
}

extern "C" void kernel_launch(void* const* d_in, const int* in_sizes, int n_in,
                              void* d_out, int out_size, void* d_ws, size_t ws_size,
                              hipStream_t stream) {
    const float* inputs = (const float*)d_in[0];
    const float* state  = (const float*)d_in[1];
    const float* kern   = (const float*)d_in[2];
    const float* rkern  = (const float*)d_in[3];

    float* out       = (float*)d_out;
    float* out_state = (float*)d_out + 8388608;

    const size_t WT_BYTES = (size_t)32 * 256 * 2048 * 2;  // 33.5 MB

    if (ws_size >= WT_BYTES) {
        unsigned short* Wt = (unsigned short*)d_ws;
        prep_w<<<dim3(32, 4, 32), 256, 0, stream>>>(kern, rkern, Wt);
        arma_gemm_mfma<<<dim3(8, 2, 32), 256, 0, stream>>>(inputs, state, Wt, out);
    } else {
        arma_gemm_f32<<<dim3(16, 4, 32), 256, 0, stream>>>(inputs, state, kern, rkern, out);
    }
    arma_assemble2<<<8388608 / 4 / 256, 256, 0, stream>>>(state, out, out_state);
}